// Round 8
// baseline (67.492 us; speedup 1.0000x reference)
//
#include <hip/hip_runtime.h>
#include <math.h>

// Problem constants (fixed by reference setup_inputs)
#define B 8
#define C 256
#define CR 64
#define H 128
#define W 128
#define HW (H*W)              // 16384 = 2^14
#define NELEM (B*C*HW)        // 33554432 = 2^25
#define N4 (NELEM/4)          // 8388608
#define PER_BATCH4 (C*HW/4)   // 1048576 = 2^20 float4 per batch
#define FUSE_BLOCKS_X 1024
#define FUSE_ITERS 4
#define FUSE_STRIDE (FUSE_BLOCKS_X*256)   // 262144, multiple of 4096

typedef float floatx4 __attribute__((ext_vector_type(4)));

__device__ __forceinline__ float sigmoidf_(float z) {
    return 1.0f / (1.0f + expf(-z));
}

// ---------------------------------------------------------------------------
// Kernel A: 8 blocks (one per batch), 256 threads. Computes cw=(B,C) and the
// 49-entry sw class table per batch (7 y-classes x 7 x-classes of in-bounds
// 7x7 tap sums). No spatial map is materialized.
// ---------------------------------------------------------------------------
__global__ __launch_bounds__(256)
void setup_kernel(const float* __restrict__ tf,   // (B,C)
                  const float* __restrict__ pw,   // (C,C) row-major [o][c]
                  const float* __restrict__ pb,   // (C,)
                  const float* __restrict__ g,    // bn_gamma
                  const float* __restrict__ be,   // bn_beta
                  const float* __restrict__ mu,   // bn_mean
                  const float* __restrict__ var,  // bn_var
                  const float* __restrict__ w1,   // (CR,C)
                  const float* __restrict__ b1,   // (CR,)
                  const float* __restrict__ w2,   // (C,CR)
                  const float* __restrict__ b2,   // (C,)
                  const float* __restrict__ saw,  // (1,2,7,7) flat
                  const float* __restrict__ sab,  // (1,)
                  float* __restrict__ cw,         // out (B,C)
                  float* __restrict__ tbl)        // out (B,49)
{
    const int b   = blockIdx.x;
    const int tid = threadIdx.x;

    __shared__ float tf_sh[C];
    __shared__ float t_sh[C];
    __shared__ float h_sh[CR];
    __shared__ float red[8];
    __shared__ float s_stats[2];   // avg, max
    __shared__ float saw_sh[98];

    tf_sh[tid] = tf[b * C + tid];
    if (tid < 98) saw_sh[tid] = saw[tid];
    __syncthreads();

    // ---- t[c] = relu(BN(proj_w[c,:]·tf[b,:] + pb[c])), thread tid = c ----
    float acc = 0.0f;
    {
        const float4* pwr = reinterpret_cast<const float4*>(pw + tid * C);
        #pragma unroll 16
        for (int k4 = 0; k4 < C / 4; ++k4) {
            const float4 wv = pwr[k4];
            const float* tfk = &tf_sh[k4 * 4];
            acc += wv.x * tfk[0] + wv.y * tfk[1] + wv.z * tfk[2] + wv.w * tfk[3];
        }
    }
    float t;
    {
        const float scale = g[tid] * rsqrtf(var[tid] + 1e-5f);
        t = (acc + pb[tid] - mu[tid]) * scale + be[tid];
        t = fmaxf(t, 0.0f);
        t_sh[tid] = t;
    }

    // ---- per-batch sum / max over C (wave shuffle + LDS combine) ----
    {
        float s = t, m = t;
        #pragma unroll
        for (int off = 32; off > 0; off >>= 1) {
            s += __shfl_down(s, off);
            m  = fmaxf(m, __shfl_down(m, off));
        }
        const int wv_ = tid >> 6;
        if ((tid & 63) == 0) { red[wv_] = s; red[4 + wv_] = m; }
        __syncthreads();
        if (tid == 0) {
            s_stats[0] = (red[0] + red[1] + red[2] + red[3]) * (1.0f / C);
            s_stats[1] = fmaxf(fmaxf(red[4], red[5]), fmaxf(red[6], red[7]));
        }
        __syncthreads();
    }

    // ---- 49-entry sw table: threads 0..48, taps from LDS ----
    if (tid < 49) {
        const int yc = tid / 7, xc = tid % 7;
        const int ky0 = yc < 3 ? 3 - yc : 0;
        const int ky1 = yc > 3 ? 9 - yc : 6;   // yc=4->5, 5->4, 6->3
        const int kx0 = xc < 3 ? 3 - xc : 0;
        const int kx1 = xc > 3 ? 9 - xc : 6;
        float S0 = 0.0f, S1 = 0.0f;
        for (int ky = ky0; ky <= ky1; ++ky)
            for (int kx = kx0; kx <= kx1; ++kx) {
                S0 += saw_sh[ky * 7 + kx];
                S1 += saw_sh[49 + ky * 7 + kx];
            }
        tbl[b * 49 + tid] = sigmoidf_(s_stats[0] * S0 + s_stats[1] * S1 + sab[0]);
    }

    // ---- h[r] = relu(ca_w1[r,:]·t + b1[r]), threads 0..63 ----
    if (tid < CR) {
        float a = b1[tid];
        const float4* w1r = reinterpret_cast<const float4*>(w1 + tid * C);
        #pragma unroll 16
        for (int k4 = 0; k4 < C / 4; ++k4) {
            const float4 wv = w1r[k4];
            const float* tk = &t_sh[k4 * 4];
            a += wv.x * tk[0] + wv.y * tk[1] + wv.z * tk[2] + wv.w * tk[3];
        }
        h_sh[tid] = fmaxf(a, 0.0f);
    }
    __syncthreads();

    // ---- cw[c] = sigmoid(ca_w2[c,:]·h + b2[c]) ----
    {
        float a = b2[tid];
        const float4* w2r = reinterpret_cast<const float4*>(w2 + tid * CR);
        #pragma unroll
        for (int r4 = 0; r4 < CR / 4; ++r4) {
            const float4 wv = w2r[r4];
            const float* hk = &h_sh[r4 * 4];
            a += wv.x * hk[0] + wv.y * hk[1] + wv.z * hk[2] + wv.w * hk[3];
        }
        cw[b * C + tid] = sigmoidf_(a);
    }
}

// ---------------------------------------------------------------------------
// Kernel C: out[b,c,y,x] = x * cw[b,c] * sw_class_value.
// Grid (1024, B): b constant per block; all spatial work hoisted.
// MLP fix: ALL 4 loads issued into registers up front (fully-unrolled static
// indexing -> registers, not scratch), then 4 multiply+nt-stores. Plain loads
// keep x L3-served; nt stores keep out from evicting x.
// ---------------------------------------------------------------------------
__global__ __launch_bounds__(256)
void fuse_kernel(const floatx4* __restrict__ x4,
                 const float*   __restrict__ cw,    // (B,C)
                 const float*   __restrict__ tbl,   // (B,49)
                 floatx4* __restrict__ out4)
{
    __shared__ float cw_sh[C];      // this batch's channel weights
    __shared__ float tbl_sh[49];    // this batch's sw class table

    const int b   = blockIdx.y;
    const int tid = threadIdx.x;
    cw_sh[tid] = cw[b * C + tid];
    if (tid < 49) tbl_sh[tid] = tbl[b * 49 + tid];
    __syncthreads();

    const int local0 = blockIdx.x * 256 + tid;     // [0, 262144)
    // spatial classification — constant across iterations
    const int s4 = local0 & 4095;                  // float4 index within plane
    const int y  = s4 >> 5;                        // 32 float4 per row
    const int xg = s4 & 31;
    const int yc = y < 3 ? y : (y > 124 ? y - 121 : 3);
    const float* tb = &tbl_sh[yc * 7];
    float s0, s1, s2, s3;
    if (xg == 0)       { s0 = tb[0]; s1 = tb[1]; s2 = tb[2]; s3 = tb[3]; }
    else if (xg == 31) { s0 = tb[3]; s1 = tb[4]; s2 = tb[5]; s3 = tb[6]; }
    else               { s0 = s1 = s2 = s3 = tb[3]; }

    const long base = (long)b * PER_BATCH4 + local0;
    const int  c0   = local0 >> 12;                // channel of iter 0

    // ---- issue all loads first (4 x 16B in flight per thread) ----
    floatx4 xs[FUSE_ITERS];
    #pragma unroll
    for (int i = 0; i < FUSE_ITERS; ++i)
        xs[i] = x4[base + (long)i * FUSE_STRIDE];

    // ---- then multiply + store ----
    #pragma unroll
    for (int i = 0; i < FUSE_ITERS; ++i) {
        const float cwv = cw_sh[c0 + i * (FUSE_STRIDE >> 12)];
        floatx4 o;
        o.x = xs[i].x * cwv * s0;
        o.y = xs[i].y * cwv * s1;
        o.z = xs[i].z * cwv * s2;
        o.w = xs[i].w * cwv * s3;
        __builtin_nontemporal_store(o, &out4[base + (long)i * FUSE_STRIDE]);
    }
}

// ---------------------------------------------------------------------------
extern "C" void kernel_launch(void* const* d_in, const int* in_sizes, int n_in,
                              void* d_out, int out_size, void* d_ws, size_t ws_size,
                              hipStream_t stream) {
    const float* x    = (const float*)d_in[0];
    const float* tf   = (const float*)d_in[1];
    const float* pw   = (const float*)d_in[2];
    const float* pb   = (const float*)d_in[3];
    const float* g    = (const float*)d_in[4];
    const float* be   = (const float*)d_in[5];
    const float* mu   = (const float*)d_in[6];
    const float* var  = (const float*)d_in[7];
    const float* w1   = (const float*)d_in[8];
    const float* b1   = (const float*)d_in[9];
    const float* w2   = (const float*)d_in[10];
    const float* b2   = (const float*)d_in[11];
    const float* saw  = (const float*)d_in[12];
    const float* sab  = (const float*)d_in[13];
    float* out = (float*)d_out;

    // workspace layout (floats): cw[2048] | tbl[392]
    float* wsf = (float*)d_ws;
    float* cw  = wsf;
    float* tbl = wsf + 2048;

    setup_kernel<<<B, 256, 0, stream>>>(tf, pw, pb, g, be, mu, var,
                                        w1, b1, w2, b2, saw, sab, cw, tbl);
    fuse_kernel<<<dim3(FUSE_BLOCKS_X, B), 256, 0, stream>>>(
        (const floatx4*)x, cw, tbl, (floatx4*)out);
}

// Round 9
// 56.599 us; speedup vs baseline: 1.1925x; 1.1925x over previous
//
#include <hip/hip_runtime.h>
#include <math.h>

// Problem constants (fixed by reference setup_inputs)
#define B 8
#define C 256
#define CR 64
#define H 128
#define W 128
#define HW (H*W)              // 16384 = 2^14
#define NELEM (B*C*HW)        // 33554432 = 2^25
#define N4 (NELEM/4)          // 8388608
#define PER_BATCH4 (C*HW/4)   // 1048576 = 2^20 float4 per batch
#define FUSE_BLOCKS_X 1024
#define FUSE_ITERS 4
#define FUSE_STRIDE (FUSE_BLOCKS_X*256)   // 262144, multiple of 4096

typedef float floatx4 __attribute__((ext_vector_type(4)));

__device__ __forceinline__ float sigmoidf_(float z) {
    return 1.0f / (1.0f + expf(-z));
}

// ---------------------------------------------------------------------------
// Kernel S1: t = relu(BN(proj_w @ tf + pb)).  Grid (8 ch-groups, 8 batches),
// 256 threads. 8 threads per output channel (each 8 float4 loads of pw),
// shfl_xor reduce. Max per-thread load depth: 8 (was 64) -> latency-parallel.
// ---------------------------------------------------------------------------
__global__ __launch_bounds__(256)
void gemv_kernel(const float* __restrict__ tf,   // (B,C)
                 const float* __restrict__ pw,   // (C,C)
                 const float* __restrict__ pb,
                 const float* __restrict__ g,
                 const float* __restrict__ be,
                 const float* __restrict__ mu,
                 const float* __restrict__ var,
                 float* __restrict__ t_out)      // (B,C)
{
    const int gx  = blockIdx.x;        // channel group 0..7
    const int b   = blockIdx.y;        // batch
    const int tid = threadIdx.x;

    __shared__ float tf_sh[C];
    tf_sh[tid] = tf[b * C + tid];

    const int ch = tid >> 3;           // 0..31
    const int c  = gx * 32 + ch;
    const int sl = tid & 7;            // 0..7, k-slice

    // prefetch BN params on writer lanes (overlaps the GEMV loads)
    float gc = 0.f, vc = 0.f, pbc = 0.f, muc = 0.f, bec = 0.f;
    if (sl == 0) { gc = g[c]; vc = var[c]; pbc = pb[c]; muc = mu[c]; bec = be[c]; }
    __syncthreads();

    float acc = 0.f;
    {
        const float4* pwr = reinterpret_cast<const float4*>(pw + c * C + sl * 32);
        const float*  tfk = &tf_sh[sl * 32];
        #pragma unroll
        for (int i = 0; i < 8; ++i) {
            const float4 wv = pwr[i];
            acc += wv.x * tfk[4*i] + wv.y * tfk[4*i+1]
                 + wv.z * tfk[4*i+2] + wv.w * tfk[4*i+3];
        }
    }
    acc += __shfl_xor(acc, 4);
    acc += __shfl_xor(acc, 2);
    acc += __shfl_xor(acc, 1);
    if (sl == 0) {
        float tv = (acc + pbc - muc) * (gc * rsqrtf(vc + 1e-5f)) + bec;
        t_out[b * C + c] = fmaxf(tv, 0.f);
    }
}

// ---------------------------------------------------------------------------
// Kernel S2: stats (avg/max over C), h = relu(w1@t+b1), cw = sigmoid(w2@h+b2),
// 49-entry sw class table. 8 blocks (one per batch), 256 threads.
// w1 sliced 4-ways per row r (16 float4 loads issued into regs BEFORE the
// barrier); tap table via fully-unrolled masked LDS broadcast reads.
// ---------------------------------------------------------------------------
__global__ __launch_bounds__(256)
void attn_kernel(const float* __restrict__ t_in,  // (B,C)
                 const float* __restrict__ w1,    // (CR,C)
                 const float* __restrict__ b1,
                 const float* __restrict__ w2,    // (C,CR)
                 const float* __restrict__ b2,
                 const float* __restrict__ saw,   // (1,2,7,7)
                 const float* __restrict__ sab,
                 float* __restrict__ cw,          // out (B,C)
                 float* __restrict__ tbl)         // out (B,49)
{
    const int b   = blockIdx.x;
    const int tid = threadIdx.x;

    __shared__ float t_sh[C];
    __shared__ float h_sh[CR];
    __shared__ float red[8];
    __shared__ float s_stats[2];
    __shared__ float saw_sh[98];

    const float tv = t_in[b * C + tid];
    t_sh[tid] = tv;
    if (tid < 98) saw_sh[tid] = saw[tid];

    // ---- issue w1 slice loads into registers (independent of t_sh) ----
    const int r  = tid >> 2;           // 0..63
    const int sl = tid & 3;            // 0..3, k-slice of 64
    float b1r = (sl == 0) ? b1[r] : 0.f;
    float4 w1v[16];
    {
        const float4* w1r = reinterpret_cast<const float4*>(w1 + r * C + sl * 64);
        #pragma unroll
        for (int i = 0; i < 16; ++i) w1v[i] = w1r[i];
    }

    // ---- per-batch sum/max over C (registers + shfl; barrier fences t_sh) --
    {
        float s = tv, m = tv;
        #pragma unroll
        for (int off = 32; off > 0; off >>= 1) {
            s += __shfl_down(s, off);
            m  = fmaxf(m, __shfl_down(m, off));
        }
        const int wv_ = tid >> 6;
        if ((tid & 63) == 0) { red[wv_] = s; red[4 + wv_] = m; }
        __syncthreads();
        if (tid == 0) {
            s_stats[0] = (red[0] + red[1] + red[2] + red[3]) * (1.0f / C);
            s_stats[1] = fmaxf(fmaxf(red[4], red[5]), fmaxf(red[6], red[7]));
        }
    }

    // ---- h[r] = relu(w1[r,:]·t + b1[r]) ----
    {
        float hacc = 0.f;
        const float* tk = &t_sh[sl * 64];
        #pragma unroll
        for (int i = 0; i < 16; ++i) {
            hacc += w1v[i].x * tk[4*i] + w1v[i].y * tk[4*i+1]
                  + w1v[i].z * tk[4*i+2] + w1v[i].w * tk[4*i+3];
        }
        hacc += __shfl_xor(hacc, 2);
        hacc += __shfl_xor(hacc, 1);
        if (sl == 0) h_sh[r] = fmaxf(hacc + b1r, 0.f);
    }
    __syncthreads();

    // ---- cw[c] = sigmoid(w2[c,:]·h + b2[c]) ----
    {
        float a = b2[tid];
        const float4* w2r = reinterpret_cast<const float4*>(w2 + tid * CR);
        #pragma unroll
        for (int r4 = 0; r4 < CR / 4; ++r4) {
            const float4 wv = w2r[r4];
            const float* hk = &h_sh[r4 * 4];
            a += wv.x * hk[0] + wv.y * hk[1] + wv.z * hk[2] + wv.w * hk[3];
        }
        cw[b * C + tid] = sigmoidf_(a);
    }

    // ---- 49-entry sw table: fully-unrolled masked broadcast LDS reads ----
    if (tid < 49) {
        const int yc = tid / 7, xc = tid % 7;
        const int ky0 = yc < 3 ? 3 - yc : 0;
        const int ky1 = yc > 3 ? 9 - yc : 6;
        const int kx0 = xc < 3 ? 3 - xc : 0;
        const int kx1 = xc > 3 ? 9 - xc : 6;
        float S0 = 0.f, S1 = 0.f;
        #pragma unroll
        for (int ky = 0; ky < 7; ++ky)
            #pragma unroll
            for (int kx = 0; kx < 7; ++kx) {
                const bool in = (ky >= ky0) & (ky <= ky1) & (kx >= kx0) & (kx <= kx1);
                S0 += in ? saw_sh[ky * 7 + kx]      : 0.f;
                S1 += in ? saw_sh[49 + ky * 7 + kx] : 0.f;
            }
        tbl[b * 49 + tid] = sigmoidf_(s_stats[0] * S0 + s_stats[1] * S1 + sab[0]);
    }
}

// ---------------------------------------------------------------------------
// Kernel C: out[b,c,y,x] = x * cw[b,c] * sw_class_value. Unchanged from R7
// (it runs at the mixed-stream ceiling; structure-insensitive).
// ---------------------------------------------------------------------------
__global__ __launch_bounds__(256)
void fuse_kernel(const floatx4* __restrict__ x4,
                 const float*   __restrict__ cw,    // (B,C)
                 const float*   __restrict__ tbl,   // (B,49)
                 floatx4* __restrict__ out4)
{
    __shared__ float cw_sh[C];
    __shared__ float tbl_sh[49];

    const int b   = blockIdx.y;
    const int tid = threadIdx.x;
    cw_sh[tid] = cw[b * C + tid];
    if (tid < 49) tbl_sh[tid] = tbl[b * 49 + tid];
    __syncthreads();

    const int local0 = blockIdx.x * 256 + tid;
    const int s4 = local0 & 4095;
    const int y  = s4 >> 5;
    const int xg = s4 & 31;
    const int yc = y < 3 ? y : (y > 124 ? y - 121 : 3);
    const float* tb = &tbl_sh[yc * 7];
    float s0, s1, s2, s3;
    if (xg == 0)       { s0 = tb[0]; s1 = tb[1]; s2 = tb[2]; s3 = tb[3]; }
    else if (xg == 31) { s0 = tb[3]; s1 = tb[4]; s2 = tb[5]; s3 = tb[6]; }
    else               { s0 = s1 = s2 = s3 = tb[3]; }

    const long base = (long)b * PER_BATCH4 + local0;
    const int  c0   = local0 >> 12;

    floatx4 xs[FUSE_ITERS];
    #pragma unroll
    for (int i = 0; i < FUSE_ITERS; ++i)
        xs[i] = x4[base + (long)i * FUSE_STRIDE];

    #pragma unroll
    for (int i = 0; i < FUSE_ITERS; ++i) {
        const float cwv = cw_sh[c0 + i * (FUSE_STRIDE >> 12)];
        floatx4 o;
        o.x = xs[i].x * cwv * s0;
        o.y = xs[i].y * cwv * s1;
        o.z = xs[i].z * cwv * s2;
        o.w = xs[i].w * cwv * s3;
        __builtin_nontemporal_store(o, &out4[base + (long)i * FUSE_STRIDE]);
    }
}

// ---------------------------------------------------------------------------
extern "C" void kernel_launch(void* const* d_in, const int* in_sizes, int n_in,
                              void* d_out, int out_size, void* d_ws, size_t ws_size,
                              hipStream_t stream) {
    const float* x    = (const float*)d_in[0];
    const float* tf   = (const float*)d_in[1];
    const float* pw   = (const float*)d_in[2];
    const float* pb   = (const float*)d_in[3];
    const float* g    = (const float*)d_in[4];
    const float* be   = (const float*)d_in[5];
    const float* mu   = (const float*)d_in[6];
    const float* var  = (const float*)d_in[7];
    const float* w1   = (const float*)d_in[8];
    const float* b1   = (const float*)d_in[9];
    const float* w2   = (const float*)d_in[10];
    const float* b2   = (const float*)d_in[11];
    const float* saw  = (const float*)d_in[12];
    const float* sab  = (const float*)d_in[13];
    float* out = (float*)d_out;

    // workspace layout (floats): t[2048] | cw[2048] | tbl[392]
    float* wsf = (float*)d_ws;
    float* t_  = wsf;
    float* cw  = wsf + 2048;
    float* tbl = wsf + 4096;

    gemv_kernel<<<dim3(8, B), 256, 0, stream>>>(tf, pw, pb, g, be, mu, var, t_);
    attn_kernel<<<B, 256, 0, stream>>>(t_, w1, b1, w2, b2, saw, sab, cw, tbl);
    fuse_kernel<<<dim3(FUSE_BLOCKS_X, B), 256, 0, stream>>>(
        (const floatx4*)x, cw, tbl, (floatx4*)out);
}